// Round 2
// baseline (5212.824 us; speedup 1.0000x reference)
//
#include <hip/hip_runtime.h>

#define TT 512
#define NSTEP 511

typedef _Float16 half8v __attribute__((ext_vector_type(8)));
typedef float floatx4 __attribute__((ext_vector_type(4)));

#if __has_builtin(__builtin_amdgcn_exp2f)
#define FAST_EXP2 __builtin_amdgcn_exp2f
#else
#define FAST_EXP2 exp2f
#endif
#if __has_builtin(__builtin_amdgcn_rcpf)
#define FAST_RCP __builtin_amdgcn_rcpf
#else
#define FAST_RCP(x) (1.0f/(x))
#endif

__device__ __forceinline__ float fast_tanh(float x) {
    // tanh(x) = 1 - 2/(1+e^{2x});  e^{2x} = 2^{x*2*log2(e)}
    float e = FAST_EXP2(x * 2.885390081777927f);
    return 1.0f - 2.0f * FAST_RCP(1.0f + e);
}

// Split a float into f16 hi + f16 lo (hi = RNE(x), lo = RNE(x - hi)).
__device__ __forceinline__ void split_f16(float x, _Float16& hi, _Float16& lo) {
    hi = (_Float16)x;
    lo = (_Float16)(x - (float)hi);
}

// One wave (64 threads) integrates 16 batch elements for all 511 Tsit5 steps.
// Matmul orientation: out[row=weight_out][col=batch] = W[row][k] * act[k][col].
// A-frag (weights): A[m=lane&15][k=quad*8+j]; B-frag (activations):
// B[k=quad*8+j][n=lane&15]; C: col(N)=lane&15, row(M)=quad*4+reg.
// All matmuls use 3-way hi/lo f16 splitting for fp32-equivalent precision:
//   W*x ~= Whi*xhi + Wlo*xhi + Whi*xlo   (fp32 accumulate)
__global__ __launch_bounds__(64, 1)
void cde_fused(const float* __restrict__ times,
               const float* __restrict__ grads,   // (B, T, 3)
               const float* __restrict__ w1, const float* __restrict__ b1,
               const float* __restrict__ w2, const float* __restrict__ b2,
               const float* __restrict__ w3, const float* __restrict__ b3,
               const float* __restrict__ w_enc, const float* __restrict__ b_enc,
               const float* __restrict__ w_ro, const float* __restrict__ b_ro,
               float* __restrict__ out)
{
    const int lane = threadIdx.x;      // 0..63
    const int col  = lane & 15;        // batch-in-tile (N) / weight row (A-m)
    const int quad = lane >> 4;        // 0..3
    const int base = blockIdx.x << 4;  // global batch base

    __shared__ __align__(16) _Float16 zbufH[16][40];   // [n][k], pad->40
    __shared__ __align__(16) _Float16 zbufL[16][40];
    __shared__ __align__(16) _Float16 h1bufH[16][72];  // [n][k], pad->72
    __shared__ __align__(16) _Float16 h1bufL[16][72];
    __shared__ __align__(16) _Float16 h2bufH[16][72];
    __shared__ __align__(16) _Float16 h2bufL[16][72];
    __shared__ __align__(16) float    dqbuf[16][4];

    // ---------------- weights -> f16 hi/lo A-fragments (VGPRs) ---------------
    half8v w1fH[4], w1fL[4], w2fH[4][2], w2fL[4][2], w3fH[6][2], w3fL[6][2];
    #pragma unroll
    for (int t = 0; t < 4; ++t) {
        const float* p = w1 + (16*t + col)*32 + quad*8;
        #pragma unroll
        for (int j = 0; j < 8; ++j) {
            _Float16 hi, lo; split_f16(p[j], hi, lo);
            w1fH[t][j] = hi; w1fL[t][j] = lo;
        }
    }
    #pragma unroll
    for (int t = 0; t < 4; ++t) {
        #pragma unroll
        for (int kt = 0; kt < 2; ++kt) {
            const float* p = w2 + (16*t + col)*64 + kt*32 + quad*8;
            #pragma unroll
            for (int j = 0; j < 8; ++j) {
                _Float16 hi, lo; split_f16(p[j], hi, lo);
                w2fH[t][kt][j] = hi; w2fL[t][kt][j] = lo;
            }
        }
    }
    // w3 rows permuted: tile t covers permuted row r' = 16t+m, with
    // c = t>>1, h = 16*(t&1)+m, original row = h*3+c. Makes k = f.dq lane-local.
    #pragma unroll
    for (int t = 0; t < 6; ++t) {
        const int c  = t >> 1;
        const int hh = t & 1;
        const int row = (16*hh + col)*3 + c;
        #pragma unroll
        for (int kt = 0; kt < 2; ++kt) {
            const float* p = w3 + row*64 + kt*32 + quad*8;
            #pragma unroll
            for (int j = 0; j < 8; ++j) {
                _Float16 hi, lo; split_f16(p[j], hi, lo);
                w3fH[t][kt][j] = hi; w3fL[t][kt][j] = lo;
            }
        }
    }

    // biases in C-layout (row = 16t + 4*quad + r), exact fp32
    float b1c[4][4], b2c[4][4], b3c[6][4];
    #pragma unroll
    for (int t = 0; t < 4; ++t)
        #pragma unroll
        for (int r = 0; r < 4; ++r) {
            b1c[t][r] = b1[16*t + 4*quad + r];
            b2c[t][r] = b2[16*t + 4*quad + r];
        }
    #pragma unroll
    for (int t = 0; t < 6; ++t) {
        const int c  = t >> 1;
        const int hh = t & 1;
        #pragma unroll
        for (int r = 0; r < 4; ++r)
            b3c[t][r] = b3[(16*hh + 4*quad + r)*3 + c];
    }

    // state z in "C32" layout: z[hh][r] = z[h = 16*hh + 4*quad + r][b = col]
    float z[2][4];
    #pragma unroll
    for (int hh = 0; hh < 2; ++hh)
        #pragma unroll
        for (int r = 0; r < 4; ++r) {
            const int h = 16*hh + 4*quad + r;
            z[hh][r] = w_enc[h] + b_enc[h];   // encoder([1.0])
        }
    const float dt = times[1] - times[0];

    // dq staging: lanes 0..47 fetch one (b,c) stream; dq[n] = grads[:,n,:]*dt
    const int lcl = lane < 48 ? lane : 47;
    const int bl  = lcl / 3;
    const int cc  = lcl - 3*bl;
    const float* gp = grads + (long)(base + bl)*(TT*3) + cc;
    const bool dqact = lane < 48;
    float dqreg = gp[0];

    static constexpr float AT[6][5] = {
        {0.f, 0.f, 0.f, 0.f, 0.f},
        {0.161f, 0.f, 0.f, 0.f, 0.f},
        {-0.008480655492356989f, 0.335480655492357f, 0.f, 0.f, 0.f},
        {2.8971530571054935f, -6.359448489975075f, 4.3622954328695815f, 0.f, 0.f},
        {5.325864828439257f, -11.748883564062828f, 7.4955393428898365f,
         -0.09249506636175525f, 0.f},
        {5.86145544294642f, -12.92096931784711f, 8.159367898576159f,
         -0.071584973281401f, -0.028269050394068383f}};
    static constexpr float BT[6] = {
        0.09646076681806523f, 0.01f, 0.4798896504144996f, 1.379008574103742f,
        -3.290069515436081f, 2.324710524099774f};

    float kk[6][2][4];
    float dq0 = 0.f, dq1 = 0.f, dq2 = 0.f;

    for (int n = 0; n < NSTEP; ++n) {
        if (dqact) *(&dqbuf[0][0] + (bl*4 + cc)) = dqreg * dt;

        #pragma unroll
        for (int s = 0; s < 6; ++s) {
            // stage argument in C32 layout
            float za[2][4];
            #pragma unroll
            for (int hh = 0; hh < 2; ++hh)
                #pragma unroll
                for (int r = 0; r < 4; ++r) {
                    float v = z[hh][r];
                    #pragma unroll
                    for (int j = 0; j < s; ++j) v += AT[s][j] * kk[j][hh][r];
                    za[hh][r] = v;
                }
            // C32 -> [n][k] LDS (f16 hi/lo)
            #pragma unroll
            for (int hh = 0; hh < 2; ++hh) {
                union { _Float16 h[4]; uint2 u; } pkH, pkL;
                #pragma unroll
                for (int r = 0; r < 4; ++r) split_f16(za[hh][r], pkH.h[r], pkL.h[r]);
                *(uint2*)&zbufH[col][16*hh + 4*quad] = pkH.u;
                *(uint2*)&zbufL[col][16*hh + 4*quad] = pkL.u;
            }
            __syncthreads();
            if (s == 0) {
                const float4 dv = *(const float4*)&dqbuf[col][0];
                dq0 = dv.x; dq1 = dv.y; dq2 = dv.z;
                const int nn = (n + 1 < NSTEP) ? (n + 1) : (NSTEP - 1);
                dqreg = gp[nn * 3];          // prefetch next step's gradient
            }
            const half8v zfH = *(const half8v*)&zbufH[col][quad*8];
            const half8v zfL = *(const half8v*)&zbufL[col][quad*8];

            // ---- layer 1: 64x32 @ 32x16 ----
            #pragma unroll
            for (int t = 0; t < 4; ++t) {
                floatx4 acc = {b1c[t][0], b1c[t][1], b1c[t][2], b1c[t][3]};
                acc = __builtin_amdgcn_mfma_f32_16x16x32_f16(w1fH[t], zfH, acc, 0, 0, 0);
                acc = __builtin_amdgcn_mfma_f32_16x16x32_f16(w1fL[t], zfH, acc, 0, 0, 0);
                acc = __builtin_amdgcn_mfma_f32_16x16x32_f16(w1fH[t], zfL, acc, 0, 0, 0);
                union { _Float16 h[4]; uint2 u; } pkH, pkL;
                #pragma unroll
                for (int r = 0; r < 4; ++r) {
                    float hv = fast_tanh(acc[r]);
                    split_f16(hv, pkH.h[r], pkL.h[r]);
                }
                *(uint2*)&h1bufH[col][16*t + 4*quad] = pkH.u;
                *(uint2*)&h1bufL[col][16*t + 4*quad] = pkL.u;
            }
            __syncthreads();
            const half8v h1f0H = *(const half8v*)&h1bufH[col][quad*8];
            const half8v h1f1H = *(const half8v*)&h1bufH[col][32 + quad*8];
            const half8v h1f0L = *(const half8v*)&h1bufL[col][quad*8];
            const half8v h1f1L = *(const half8v*)&h1bufL[col][32 + quad*8];

            // ---- layer 2: 64x64 @ 64x16 ----
            #pragma unroll
            for (int t = 0; t < 4; ++t) {
                floatx4 acc = {b2c[t][0], b2c[t][1], b2c[t][2], b2c[t][3]};
                acc = __builtin_amdgcn_mfma_f32_16x16x32_f16(w2fH[t][0], h1f0H, acc, 0, 0, 0);
                acc = __builtin_amdgcn_mfma_f32_16x16x32_f16(w2fL[t][0], h1f0H, acc, 0, 0, 0);
                acc = __builtin_amdgcn_mfma_f32_16x16x32_f16(w2fH[t][0], h1f0L, acc, 0, 0, 0);
                acc = __builtin_amdgcn_mfma_f32_16x16x32_f16(w2fH[t][1], h1f1H, acc, 0, 0, 0);
                acc = __builtin_amdgcn_mfma_f32_16x16x32_f16(w2fL[t][1], h1f1H, acc, 0, 0, 0);
                acc = __builtin_amdgcn_mfma_f32_16x16x32_f16(w2fH[t][1], h1f1L, acc, 0, 0, 0);
                union { _Float16 h[4]; uint2 u; } pkH, pkL;
                #pragma unroll
                for (int r = 0; r < 4; ++r) {
                    float hv = fast_tanh(acc[r]);
                    split_f16(hv, pkH.h[r], pkL.h[r]);
                }
                *(uint2*)&h2bufH[col][16*t + 4*quad] = pkH.u;
                *(uint2*)&h2bufL[col][16*t + 4*quad] = pkL.u;
            }
            __syncthreads();
            const half8v h2f0H = *(const half8v*)&h2bufH[col][quad*8];
            const half8v h2f1H = *(const half8v*)&h2bufH[col][32 + quad*8];
            const half8v h2f0L = *(const half8v*)&h2bufL[col][quad*8];
            const half8v h2f1L = *(const half8v*)&h2bufL[col][32 + quad*8];

            // ---- layer 3: 96x64 @ 64x16 (rows permuted to c*32+h) ----
            float a3[6][4];
            #pragma unroll
            for (int t = 0; t < 6; ++t) {
                floatx4 acc = {b3c[t][0], b3c[t][1], b3c[t][2], b3c[t][3]};
                acc = __builtin_amdgcn_mfma_f32_16x16x32_f16(w3fH[t][0], h2f0H, acc, 0, 0, 0);
                acc = __builtin_amdgcn_mfma_f32_16x16x32_f16(w3fL[t][0], h2f0H, acc, 0, 0, 0);
                acc = __builtin_amdgcn_mfma_f32_16x16x32_f16(w3fH[t][0], h2f0L, acc, 0, 0, 0);
                acc = __builtin_amdgcn_mfma_f32_16x16x32_f16(w3fH[t][1], h2f1H, acc, 0, 0, 0);
                acc = __builtin_amdgcn_mfma_f32_16x16x32_f16(w3fL[t][1], h2f1H, acc, 0, 0, 0);
                acc = __builtin_amdgcn_mfma_f32_16x16x32_f16(w3fH[t][1], h2f1L, acc, 0, 0, 0);
                #pragma unroll
                for (int r = 0; r < 4; ++r) a3[t][r] = acc[r];
            }
            // k_s[h][b] = sum_c f[c*32+h][b] * dq[b][c]  (lane-local)
            #pragma unroll
            for (int hh = 0; hh < 2; ++hh)
                #pragma unroll
                for (int r = 0; r < 4; ++r)
                    kk[s][hh][r] = a3[hh][r]*dq0 + a3[2+hh][r]*dq1 + a3[4+hh][r]*dq2;
        }

        // z += sum_i B_i * k_i
        #pragma unroll
        for (int hh = 0; hh < 2; ++hh)
            #pragma unroll
            for (int r = 0; r < 4; ++r) {
                float v = z[hh][r];
                #pragma unroll
                for (int j = 0; j < 6; ++j) v += BT[j] * kk[j][hh][r];
                z[hh][r] = v;
            }
    }

    // ---- readout: logit[b] = sum_h z[h][b]*w_ro[h] + b_ro; out = sigmoid ----
    float part = 0.f;
    #pragma unroll
    for (int hh = 0; hh < 2; ++hh)
        #pragma unroll
        for (int r = 0; r < 4; ++r) {
            const int h = 16*hh + 4*quad + r;
            part += z[hh][r] * w_ro[h];
        }
    part += __shfl_xor(part, 16, 64);
    part += __shfl_xor(part, 32, 64);
    if (lane < 16) {
        const float x = part + b_ro[0];
        out[base + col] = FAST_RCP(1.0f + FAST_EXP2(-1.4426950408889634f * x));
    }
}

extern "C" void kernel_launch(void* const* d_in, const int* in_sizes, int n_in,
                              void* d_out, int out_size, void* d_ws, size_t ws_size,
                              hipStream_t stream) {
    const float* times = (const float*)d_in[0];
    const float* grads = (const float*)d_in[1];
    const float* w1    = (const float*)d_in[2];
    const float* b1    = (const float*)d_in[3];
    const float* w2    = (const float*)d_in[4];
    const float* b2    = (const float*)d_in[5];
    const float* w3    = (const float*)d_in[6];
    const float* b3    = (const float*)d_in[7];
    const float* w_enc = (const float*)d_in[8];
    const float* b_enc = (const float*)d_in[9];
    const float* w_ro  = (const float*)d_in[10];
    const float* b_ro  = (const float*)d_in[11];

    const int B = in_sizes[1] / (TT * 3);   // 16384
    dim3 grid(B / 16), block(64);
    hipLaunchKernelGGL(cde_fused, grid, block, 0, stream,
                       times, grads, w1, b1, w2, b2, w3, b3,
                       w_enc, b_enc, w_ro, b_ro, (float*)d_out);
}

// Round 3
// 4732.536 us; speedup vs baseline: 1.1015x; 1.1015x over previous
//
#include <hip/hip_runtime.h>

#define TT 512
#define NSTEP 511

typedef _Float16 half8v __attribute__((ext_vector_type(8)));
typedef float floatx4 __attribute__((ext_vector_type(4)));

#if __has_builtin(__builtin_amdgcn_exp2f)
#define FAST_EXP2 __builtin_amdgcn_exp2f
#else
#define FAST_EXP2 exp2f
#endif
#if __has_builtin(__builtin_amdgcn_rcpf)
#define FAST_RCP __builtin_amdgcn_rcpf
#else
#define FAST_RCP(x) (1.0f/(x))
#endif

__device__ __forceinline__ float fast_tanh(float x) {
    float e = FAST_EXP2(x * 2.885390081777927f);
    return 1.0f - 2.0f * FAST_RCP(1.0f + e);
}

__device__ __forceinline__ void split_f16(float x, _Float16& hi, _Float16& lo) {
    hi = (_Float16)x;
    lo = (_Float16)(x - (float)hi);
}

// Two waves (128 threads) per 16-batch tile; wave w owns M-rows [32w,32w+32)
// of layers 1/2 and the hh=w half (rows [16w,16w+16)) of layer 3 / state z.
// Cross-wave data flows through the existing za/h1/h2 LDS exchanges.
// A-frag (weights): A[m=lane&15][k=quad*8+j]; B-frag (activations):
// B[k=quad*8+j][n=lane&15]; C: col(N)=lane&15, row(M)=quad*4+reg.
// 3-way hi/lo f16 split: W*x ~= Whi*xhi + Wlo*xhi + Whi*xlo (fp32 acc).
__global__ __launch_bounds__(128, 2)
void cde_fused(const float* __restrict__ times,
               const float* __restrict__ grads,   // (B, T, 3)
               const float* __restrict__ w1, const float* __restrict__ b1,
               const float* __restrict__ w2, const float* __restrict__ b2,
               const float* __restrict__ w3, const float* __restrict__ b3,
               const float* __restrict__ w_enc, const float* __restrict__ b_enc,
               const float* __restrict__ w_ro, const float* __restrict__ b_ro,
               float* __restrict__ out)
{
    const int tid  = threadIdx.x;      // 0..127
    const int wid  = tid >> 6;         // wave id: 0,1
    const int lane = tid & 63;
    const int col  = lane & 15;        // batch-in-tile (N) / weight row (A-m)
    const int quad = lane >> 4;        // 0..3
    const int base = blockIdx.x << 4;  // global batch base

    __shared__ __align__(16) _Float16 zbufH[16][40];   // [n][k], pad->40
    __shared__ __align__(16) _Float16 zbufL[16][40];
    __shared__ __align__(16) _Float16 h1bufH[16][72];  // [n][k], pad->72
    __shared__ __align__(16) _Float16 h1bufL[16][72];
    __shared__ __align__(16) _Float16 h2bufH[16][72];
    __shared__ __align__(16) _Float16 h2bufL[16][72];
    __shared__ __align__(16) float    dqbuf[16][4];
    __shared__ __align__(16) float    robuf[16];

    // -------- weights -> f16 hi/lo A-fragments (this wave's halves) ---------
    half8v w1fH[2], w1fL[2], w2fH[2][2], w2fL[2][2], w3fH[3][2], w3fL[3][2];
    #pragma unroll
    for (int tt = 0; tt < 2; ++tt) {
        const int T = 2*wid + tt;
        const float* p = w1 + (16*T + col)*32 + quad*8;
        #pragma unroll
        for (int j = 0; j < 8; ++j) {
            _Float16 hi, lo; split_f16(p[j], hi, lo);
            w1fH[tt][j] = hi; w1fL[tt][j] = lo;
        }
    }
    #pragma unroll
    for (int tt = 0; tt < 2; ++tt) {
        const int T = 2*wid + tt;
        #pragma unroll
        for (int kt = 0; kt < 2; ++kt) {
            const float* p = w2 + (16*T + col)*64 + kt*32 + quad*8;
            #pragma unroll
            for (int j = 0; j < 8; ++j) {
                _Float16 hi, lo; split_f16(p[j], hi, lo);
                w2fH[tt][kt][j] = hi; w2fL[tt][kt][j] = lo;
            }
        }
    }
    // L3: wave w takes c=0..2 of rows h = 16*wid + m (orig row = h*3+c).
    #pragma unroll
    for (int c = 0; c < 3; ++c) {
        const int row = (16*wid + col)*3 + c;
        #pragma unroll
        for (int kt = 0; kt < 2; ++kt) {
            const float* p = w3 + row*64 + kt*32 + quad*8;
            #pragma unroll
            for (int j = 0; j < 8; ++j) {
                _Float16 hi, lo; split_f16(p[j], hi, lo);
                w3fH[c][kt][j] = hi; w3fL[c][kt][j] = lo;
            }
        }
    }

    // biases in C-layout
    float b1c[2][4], b2c[2][4], b3c[3][4];
    #pragma unroll
    for (int tt = 0; tt < 2; ++tt) {
        const int T = 2*wid + tt;
        #pragma unroll
        for (int r = 0; r < 4; ++r) {
            b1c[tt][r] = b1[16*T + 4*quad + r];
            b2c[tt][r] = b2[16*T + 4*quad + r];
        }
    }
    #pragma unroll
    for (int c = 0; c < 3; ++c)
        #pragma unroll
        for (int r = 0; r < 4; ++r)
            b3c[c][r] = b3[(16*wid + 4*quad + r)*3 + c];

    // state z rows owned by this wave: h = 16*wid + 4*quad + r
    float z[4];
    #pragma unroll
    for (int r = 0; r < 4; ++r) {
        const int h = 16*wid + 4*quad + r;
        z[r] = w_enc[h] + b_enc[h];   // encoder([1.0])
    }
    const float dt = times[1] - times[0];

    // dq staging: threads 0..47 (wave 0) fetch one (b,c) stream
    const int lcl = tid < 48 ? tid : 47;
    const int bl  = lcl / 3;
    const int cc  = lcl - 3*bl;
    const float* gp = grads + (long)(base + bl)*(TT*3) + cc;
    const bool dqact = tid < 48;
    float dqreg = gp[0];

    static constexpr float AT[6][5] = {
        {0.f, 0.f, 0.f, 0.f, 0.f},
        {0.161f, 0.f, 0.f, 0.f, 0.f},
        {-0.008480655492356989f, 0.335480655492357f, 0.f, 0.f, 0.f},
        {2.8971530571054935f, -6.359448489975075f, 4.3622954328695815f, 0.f, 0.f},
        {5.325864828439257f, -11.748883564062828f, 7.4955393428898365f,
         -0.09249506636175525f, 0.f},
        {5.86145544294642f, -12.92096931784711f, 8.159367898576159f,
         -0.071584973281401f, -0.028269050394068383f}};
    static constexpr float BT[6] = {
        0.09646076681806523f, 0.01f, 0.4798896504144996f, 1.379008574103742f,
        -3.290069515436081f, 2.324710524099774f};

    float kk[6][4];
    float dq0 = 0.f, dq1 = 0.f, dq2 = 0.f;

    for (int n = 0; n < NSTEP; ++n) {
        if (dqact) *(&dqbuf[0][0] + (bl*4 + cc)) = dqreg * dt;

        #pragma unroll
        for (int s = 0; s < 6; ++s) {
            // stage argument (this wave's 16 rows), C-layout
            float za[4];
            #pragma unroll
            for (int r = 0; r < 4; ++r) {
                float v = z[r];
                #pragma unroll
                for (int j = 0; j < s; ++j) v += AT[s][j] * kk[j][r];
                za[r] = v;
            }
            {
                union { _Float16 h[4]; uint2 u; } pkH, pkL;
                #pragma unroll
                for (int r = 0; r < 4; ++r) split_f16(za[r], pkH.h[r], pkL.h[r]);
                *(uint2*)&zbufH[col][16*wid + 4*quad] = pkH.u;
                *(uint2*)&zbufL[col][16*wid + 4*quad] = pkL.u;
            }
            __syncthreads();
            if (s == 0) {
                const float4 dv = *(const float4*)&dqbuf[col][0];
                dq0 = dv.x; dq1 = dv.y; dq2 = dv.z;
                const int nn = (n + 1 < NSTEP) ? (n + 1) : (NSTEP - 1);
                dqreg = gp[nn * 3];          // prefetch next step's gradient
            }
            const half8v zfH = *(const half8v*)&zbufH[col][quad*8];
            const half8v zfL = *(const half8v*)&zbufL[col][quad*8];

            // ---- layer 1: this wave's 32 rows ----
            #pragma unroll
            for (int tt = 0; tt < 2; ++tt) {
                floatx4 acc = {b1c[tt][0], b1c[tt][1], b1c[tt][2], b1c[tt][3]};
                acc = __builtin_amdgcn_mfma_f32_16x16x32_f16(w1fH[tt], zfH, acc, 0, 0, 0);
                acc = __builtin_amdgcn_mfma_f32_16x16x32_f16(w1fL[tt], zfH, acc, 0, 0, 0);
                acc = __builtin_amdgcn_mfma_f32_16x16x32_f16(w1fH[tt], zfL, acc, 0, 0, 0);
                union { _Float16 h[4]; uint2 u; } pkH, pkL;
                #pragma unroll
                for (int r = 0; r < 4; ++r) {
                    float hv = fast_tanh(acc[r]);
                    split_f16(hv, pkH.h[r], pkL.h[r]);
                }
                *(uint2*)&h1bufH[col][32*wid + 16*tt + 4*quad] = pkH.u;
                *(uint2*)&h1bufL[col][32*wid + 16*tt + 4*quad] = pkL.u;
            }
            __syncthreads();
            const half8v h1f0H = *(const half8v*)&h1bufH[col][quad*8];
            const half8v h1f1H = *(const half8v*)&h1bufH[col][32 + quad*8];
            const half8v h1f0L = *(const half8v*)&h1bufL[col][quad*8];
            const half8v h1f1L = *(const half8v*)&h1bufL[col][32 + quad*8];

            // ---- layer 2: this wave's 32 rows ----
            #pragma unroll
            for (int tt = 0; tt < 2; ++tt) {
                floatx4 acc = {b2c[tt][0], b2c[tt][1], b2c[tt][2], b2c[tt][3]};
                acc = __builtin_amdgcn_mfma_f32_16x16x32_f16(w2fH[tt][0], h1f0H, acc, 0, 0, 0);
                acc = __builtin_amdgcn_mfma_f32_16x16x32_f16(w2fL[tt][0], h1f0H, acc, 0, 0, 0);
                acc = __builtin_amdgcn_mfma_f32_16x16x32_f16(w2fH[tt][0], h1f0L, acc, 0, 0, 0);
                acc = __builtin_amdgcn_mfma_f32_16x16x32_f16(w2fH[tt][1], h1f1H, acc, 0, 0, 0);
                acc = __builtin_amdgcn_mfma_f32_16x16x32_f16(w2fL[tt][1], h1f1H, acc, 0, 0, 0);
                acc = __builtin_amdgcn_mfma_f32_16x16x32_f16(w2fH[tt][1], h1f1L, acc, 0, 0, 0);
                union { _Float16 h[4]; uint2 u; } pkH, pkL;
                #pragma unroll
                for (int r = 0; r < 4; ++r) {
                    float hv = fast_tanh(acc[r]);
                    split_f16(hv, pkH.h[r], pkL.h[r]);
                }
                *(uint2*)&h2bufH[col][32*wid + 16*tt + 4*quad] = pkH.u;
                *(uint2*)&h2bufL[col][32*wid + 16*tt + 4*quad] = pkL.u;
            }
            __syncthreads();
            const half8v h2f0H = *(const half8v*)&h2bufH[col][quad*8];
            const half8v h2f1H = *(const half8v*)&h2bufH[col][32 + quad*8];
            const half8v h2f0L = *(const half8v*)&h2bufL[col][quad*8];
            const half8v h2f1L = *(const half8v*)&h2bufL[col][32 + quad*8];

            // ---- layer 3: c = 0..2 of this wave's hh half ----
            float a3[3][4];
            #pragma unroll
            for (int c = 0; c < 3; ++c) {
                floatx4 acc = {b3c[c][0], b3c[c][1], b3c[c][2], b3c[c][3]};
                acc = __builtin_amdgcn_mfma_f32_16x16x32_f16(w3fH[c][0], h2f0H, acc, 0, 0, 0);
                acc = __builtin_amdgcn_mfma_f32_16x16x32_f16(w3fL[c][0], h2f0H, acc, 0, 0, 0);
                acc = __builtin_amdgcn_mfma_f32_16x16x32_f16(w3fH[c][0], h2f0L, acc, 0, 0, 0);
                acc = __builtin_amdgcn_mfma_f32_16x16x32_f16(w3fH[c][1], h2f1H, acc, 0, 0, 0);
                acc = __builtin_amdgcn_mfma_f32_16x16x32_f16(w3fL[c][1], h2f1H, acc, 0, 0, 0);
                acc = __builtin_amdgcn_mfma_f32_16x16x32_f16(w3fH[c][1], h2f1L, acc, 0, 0, 0);
                #pragma unroll
                for (int r = 0; r < 4; ++r) a3[c][r] = acc[r];
            }
            #pragma unroll
            for (int r = 0; r < 4; ++r)
                kk[s][r] = a3[0][r]*dq0 + a3[1][r]*dq1 + a3[2][r]*dq2;
        }

        // z += sum_i B_i * k_i
        #pragma unroll
        for (int r = 0; r < 4; ++r) {
            float v = z[r];
            #pragma unroll
            for (int j = 0; j < 6; ++j) v += BT[j] * kk[j][r];
            z[r] = v;
        }
    }

    // ---- readout: logit[b] = sum_h z[h][b]*w_ro[h] + b_ro; out = sigmoid ----
    float part = 0.f;
    #pragma unroll
    for (int r = 0; r < 4; ++r)
        part += z[r] * w_ro[16*wid + 4*quad + r];
    part += __shfl_xor(part, 16, 64);
    part += __shfl_xor(part, 32, 64);
    if (wid == 1 && lane < 16) robuf[col] = part;
    __syncthreads();
    if (wid == 0 && lane < 16) {
        const float x = part + robuf[col] + b_ro[0];
        out[base + col] = FAST_RCP(1.0f + FAST_EXP2(-1.4426950408889634f * x));
    }
}

extern "C" void kernel_launch(void* const* d_in, const int* in_sizes, int n_in,
                              void* d_out, int out_size, void* d_ws, size_t ws_size,
                              hipStream_t stream) {
    const float* times = (const float*)d_in[0];
    const float* grads = (const float*)d_in[1];
    const float* w1    = (const float*)d_in[2];
    const float* b1    = (const float*)d_in[3];
    const float* w2    = (const float*)d_in[4];
    const float* b2    = (const float*)d_in[5];
    const float* w3    = (const float*)d_in[6];
    const float* b3    = (const float*)d_in[7];
    const float* w_enc = (const float*)d_in[8];
    const float* b_enc = (const float*)d_in[9];
    const float* w_ro  = (const float*)d_in[10];
    const float* b_ro  = (const float*)d_in[11];

    const int B = in_sizes[1] / (TT * 3);   // 16384
    dim3 grid(B / 16), block(128);
    hipLaunchKernelGGL(cde_fused, grid, block, 0, stream,
                       times, grads, w1, b1, w2, b2, w3, b3,
                       w_enc, b_enc, w_ro, b_ro, (float*)d_out);
}